// Round 1
// baseline (4575.626 us; speedup 1.0000x reference)
//
#include <hip/hip_runtime.h>
#include <math.h>

#define B 32
#define S 4096
#define N 1024

#define RT 64   // rows (b*s) per block in score kernel
#define MT 64   // m columns per block
#define KT 16   // k tile

// ---------------------------------------------------------------------------
// Kernel 1: dec_feats[b][m] = dot(dec_in_state[b], Ws[m]) + bs[m]
// Thread layout: b = tid&31 (fast), m = tid>>5 -> Ws row broadcast within wave.
// ---------------------------------------------------------------------------
__global__ __launch_bounds__(256)
void dec_feats_kernel(const float* __restrict__ dec, const float* __restrict__ Ws,
                      const float* __restrict__ bs, float* __restrict__ dec_feats) {
    int t = blockIdx.x * blockDim.x + threadIdx.x; // 0 .. B*N-1
    int b = t & (B - 1);
    int m = t >> 5;
    const float4* drow = (const float4*)(dec + (size_t)b * N);
    const float4* wrow = (const float4*)(Ws + (size_t)m * N);
    float acc = 0.f;
    for (int n4 = 0; n4 < N / 4; ++n4) {
        float4 a = drow[n4];
        float4 w = wrow[n4];
        acc += a.x * w.x + a.y * w.y + a.z * w.z + a.w * w.w;
    }
    dec_feats[(size_t)b * N + m] = acc + bs[m];
}

// ---------------------------------------------------------------------------
// Kernel 2: the big fused GEMM.
// e[r] += sum_{m in tile} tanh( enc[r]·Wh[m] + bh[m] + dec_feats[b][m]
//                               + cov[r]*wc[m] ) * v[m]
// Block = 256 threads, 64x64 output tile, full K loop (1024).
// atomicAdd partial e per row (16 m-tiles contribute per row).
// ---------------------------------------------------------------------------
__global__ __launch_bounds__(256)
void score_kernel(const float* __restrict__ enc, const float* __restrict__ Wh,
                  const float* __restrict__ bh, const float* __restrict__ dec_feats,
                  const float* __restrict__ cov, const float* __restrict__ wc,
                  const float* __restrict__ v, float* __restrict__ e) {
    __shared__ float As[KT][RT];
    __shared__ float Bs[KT][MT];

    // XCD-aware swizzle: the 16 m-tiles of one row-tile map to HW blocks with
    // stride 8 -> same XCD (round-robin dispatch) -> A tile stays in that L2.
    unsigned h   = blockIdx.x;
    unsigned x   = h & 7u;
    unsigned j   = h >> 3;
    unsigned t16 = j >> 4;
    unsigned mt  = j & 15u;
    unsigned g   = x + 8u * t16;     // row tile 0..2047
    int r0 = (int)g * RT;
    int m0 = (int)mt * MT;

    int t  = threadIdx.x;
    int tx = t & 15;     // m sub-tile
    int ty = t >> 4;     // row sub-tile

    float acc[4][4] = {};
    int lr = t >> 2;          // 0..63 (row within tile for staging)
    int lk = (t & 3) * 4;     // 0,4,8,12 (k within tile)

    for (int k0 = 0; k0 < N; k0 += KT) {
        float4 a4 = *(const float4*)(enc + (size_t)(r0 + lr) * N + k0 + lk);
        As[lk + 0][lr] = a4.x; As[lk + 1][lr] = a4.y;
        As[lk + 2][lr] = a4.z; As[lk + 3][lr] = a4.w;
        float4 b4 = *(const float4*)(Wh + (size_t)(m0 + lr) * N + k0 + lk);
        Bs[lk + 0][lr] = b4.x; Bs[lk + 1][lr] = b4.y;
        Bs[lk + 2][lr] = b4.z; Bs[lk + 3][lr] = b4.w;
        __syncthreads();
#pragma unroll
        for (int kk = 0; kk < KT; ++kk) {
            float4 av = *(const float4*)&As[kk][ty * 4];
            float4 bv = *(const float4*)&Bs[kk][tx * 4];
            float ar[4] = {av.x, av.y, av.z, av.w};
            float br[4] = {bv.x, bv.y, bv.z, bv.w};
#pragma unroll
            for (int i = 0; i < 4; ++i)
#pragma unroll
                for (int jj = 0; jj < 4; ++jj)
                    acc[i][jj] += ar[i] * br[jj];
        }
        __syncthreads();
    }

    // Epilogue: bias + dec + coverage, tanh, dot with v over this m-tile.
    float partial[4];
#pragma unroll
    for (int i = 0; i < 4; ++i) {
        int r  = r0 + ty * 4 + i;
        int bb = r >> 12;            // r / S  (S = 4096)
        float cv = cov[r];
        float p = 0.f;
#pragma unroll
        for (int jj = 0; jj < 4; ++jj) {
            int mm = m0 + tx * 4 + jj;
            float val = acc[i][jj] + bh[mm] + dec_feats[(size_t)bb * N + mm] + cv * wc[mm];
            p += tanhf(val) * v[mm];
        }
        partial[i] = p;
    }
    // Reduce over the 16 tx lanes (low 4 bits of lane id within wave64).
#pragma unroll
    for (int i = 0; i < 4; ++i) {
        float p = partial[i];
        p += __shfl_xor(p, 1);
        p += __shfl_xor(p, 2);
        p += __shfl_xor(p, 4);
        p += __shfl_xor(p, 8);
        if (tx == 0) atomicAdd(&e[r0 + ty * 4 + i], p);
    }
}

// ---------------------------------------------------------------------------
// Kernel 3: masked softmax (renormalized masked softmax == plain masked
// softmax algebraically) + coverage update. One block per batch row.
// ---------------------------------------------------------------------------
__global__ __launch_bounds__(256)
void softmax_kernel(const float* __restrict__ e, const int* __restrict__ lens,
                    const float* __restrict__ cov,
                    float* __restrict__ attn, float* __restrict__ cov_out) {
    int b = blockIdx.x;
    int len = lens[b];
    const float* eb = e + (size_t)b * S;
    __shared__ float red[256];
    int t = threadIdx.x;

    float mx = -INFINITY;
    for (int s = t; s < S; s += 256)
        if (s < len) mx = fmaxf(mx, eb[s]);
    red[t] = mx; __syncthreads();
    for (int off = 128; off > 0; off >>= 1) {
        if (t < off) red[t] = fmaxf(red[t], red[t + off]);
        __syncthreads();
    }
    mx = red[0]; __syncthreads();

    float sum = 0.f;
    for (int s = t; s < S; s += 256)
        if (s < len) sum += __expf(eb[s] - mx);
    red[t] = sum; __syncthreads();
    for (int off = 128; off > 0; off >>= 1) {
        if (t < off) red[t] += red[t + off];
        __syncthreads();
    }
    float inv = 1.f / red[0];

    for (int s = t; s < S; s += 256) {
        float a = (s < len) ? __expf(eb[s] - mx) * inv : 0.f;
        attn[(size_t)b * S + s] = a;
        cov_out[(size_t)b * S + s] = cov[(size_t)b * S + s] + a;
    }
}

// ---------------------------------------------------------------------------
// Kernel 4: context[b][n] = sum_s attn[b][s] * enc[b][s][n]
// Grid (s-chunk, b); each block covers all 1024 n via 256 threads x float4,
// loops over its s range, atomicAdds into zeroed context.
// ---------------------------------------------------------------------------
#define SCH 32
__global__ __launch_bounds__(256)
void context_kernel(const float* __restrict__ attn, const float* __restrict__ enc,
                    float* __restrict__ ctx) {
    int b  = blockIdx.y;
    int s0 = blockIdx.x * (S / SCH);
    int n4 = threadIdx.x;     // float4 column group: columns n4*4..n4*4+3
    const float4* ep = (const float4*)(enc + ((size_t)b * S + s0) * N);
    float4 acc = {0.f, 0.f, 0.f, 0.f};
    for (int s = 0; s < S / SCH; ++s) {
        float a = attn[(size_t)b * S + s0 + s];
        float4 ev = ep[(size_t)s * (N / 4) + n4];
        acc.x += a * ev.x; acc.y += a * ev.y;
        acc.z += a * ev.z; acc.w += a * ev.w;
    }
    float* cp = ctx + (size_t)b * N + n4 * 4;
    atomicAdd(cp + 0, acc.x);
    atomicAdd(cp + 1, acc.y);
    atomicAdd(cp + 2, acc.z);
    atomicAdd(cp + 3, acc.w);
}

// ---------------------------------------------------------------------------
extern "C" void kernel_launch(void* const* d_in, const int* in_sizes, int n_in,
                              void* d_out, int out_size, void* d_ws, size_t ws_size,
                              hipStream_t stream) {
    const float* dec  = (const float*)d_in[0];
    const float* enc  = (const float*)d_in[1];
    const int*   lens = (const int*)  d_in[2];
    const float* cov  = (const float*)d_in[3];
    const float* Wh   = (const float*)d_in[4];
    const float* bh   = (const float*)d_in[5];
    const float* Ws   = (const float*)d_in[6];
    const float* bs   = (const float*)d_in[7];
    const float* wc   = (const float*)d_in[8];
    const float* v    = (const float*)d_in[9];

    float* out     = (float*)d_out;
    float* ctx     = out;                    // B*N
    float* attn    = out + (size_t)B * N;    // B*S
    float* cov_out = attn + (size_t)B * S;   // B*S

    float* dec_feats = (float*)d_ws;                     // B*N floats
    float* e         = dec_feats + (size_t)B * N;        // B*S floats

    // ws/out are poisoned each call: zero the accumulation targets.
    hipMemsetAsync(e, 0, (size_t)B * S * sizeof(float), stream);
    hipMemsetAsync(ctx, 0, (size_t)B * N * sizeof(float), stream);

    dec_feats_kernel<<<(B * N) / 256, 256, 0, stream>>>(dec, Ws, bs, dec_feats);
    score_kernel<<<(B * S / RT) * (N / MT), 256, 0, stream>>>(
        enc, Wh, bh, dec_feats, cov, wc, v, e);
    softmax_kernel<<<B, 256, 0, stream>>>(e, lens, cov, attn, cov_out);
    context_kernel<<<dim3(SCH, B), 256, 0, stream>>>(attn, enc, ctx);
}

// Round 2
// 1416.388 us; speedup vs baseline: 3.2305x; 3.2305x over previous
//
#include <hip/hip_runtime.h>
#include <math.h>

#define B 32
#define S 4096
#define N 1024

typedef short short8 __attribute__((ext_vector_type(8)));
typedef short short4v __attribute__((ext_vector_type(4)));
typedef float float4v __attribute__((ext_vector_type(4)));

__device__ inline short f2bf(float f) {
    unsigned u = __builtin_bit_cast(unsigned, f);
    u += 0x7fffu + ((u >> 16) & 1u);   // RNE
    return (short)(u >> 16);
}

// ---------------------------------------------------------------------------
// Kernel 1: dec_feats[b][m] = dot(dec_in_state[b], Ws[m]) + bs[m]  (fp32, tiny)
// ---------------------------------------------------------------------------
__global__ __launch_bounds__(256)
void dec_feats_kernel(const float* __restrict__ dec, const float* __restrict__ Ws,
                      const float* __restrict__ bs, float* __restrict__ dec_feats) {
    int t = blockIdx.x * blockDim.x + threadIdx.x; // 0 .. B*N-1
    int b = t & (B - 1);
    int m = t >> 5;
    const float4* drow = (const float4*)(dec + (size_t)b * N);
    const float4* wrow = (const float4*)(Ws + (size_t)m * N);
    float acc = 0.f;
    for (int n4 = 0; n4 < N / 4; ++n4) {
        float4 a = drow[n4];
        float4 w = wrow[n4];
        acc += a.x * w.x + a.y * w.y + a.z * w.z + a.w * w.w;
    }
    dec_feats[(size_t)b * N + m] = acc + bs[m];
}

// ---------------------------------------------------------------------------
// Kernel 2: fused score GEMM via bf16 MFMA.
// e[r] += sum_m tanh( enc[r]·Wh[m] + bh[m] + dec_feats[b][m] + cov[r]*wc[m] ) * v[m]
// 128x128 tile, 4 waves, each wave a 64x64 quadrant of 4x4 16x16x32 MFMAs.
// fp32->bf16 conversion happens during LDS staging.
// ---------------------------------------------------------------------------
#define BR 128
#define BM 128
#define BK 64
#define LDK (BK + 8)   // 72 shorts = 144 B row stride: 2-way LDS aliasing only (free)

__global__ __launch_bounds__(256)
void score_mfma_kernel(const float* __restrict__ enc, const float* __restrict__ Wh,
                       const float* __restrict__ bh, const float* __restrict__ dec_feats,
                       const float* __restrict__ cov, const float* __restrict__ wc,
                       const float* __restrict__ v, float* __restrict__ e) {
    __shared__ short As[BR][LDK];
    __shared__ short Bs[BM][LDK];

    // XCD swizzle: the 8 m-tiles of one row-tile share h&7 -> same XCD ->
    // A rows fetched once per XCD L2; dispatched within a 64-block window.
    unsigned h   = blockIdx.x;
    unsigned xcd = h & 7u;
    unsigned mt  = (h >> 3) & 7u;
    unsigned g   = h >> 6;
    int r0 = (int)(xcd + 8u * g) * BR;   // row tile 0..1023
    int m0 = (int)mt * BM;

    int t    = threadIdx.x;
    int lane = t & 63;
    int w    = t >> 6;
    int wr   = (w >> 1) * 64;
    int wm   = (w & 1) * 64;
    int cq   = lane >> 4;   // 0..3
    int cm   = lane & 15;

    float4v acc[4][4];
#pragma unroll
    for (int i = 0; i < 4; ++i)
#pragma unroll
        for (int j = 0; j < 4; ++j) acc[i][j] = (float4v){0.f, 0.f, 0.f, 0.f};

    int srow = t >> 4;          // 0..15
    int scol = (t & 15) * 4;    // 0..60

    for (int k0 = 0; k0 < N; k0 += BK) {
#pragma unroll
        for (int p = 0; p < 8; ++p) {
            int row = p * 16 + srow;
            float4v a = *(const float4v*)(enc + (size_t)(r0 + row) * N + k0 + scol);
            short4v ap = { f2bf(a.x), f2bf(a.y), f2bf(a.z), f2bf(a.w) };
            *(short4v*)&As[row][scol] = ap;
            float4v bq = *(const float4v*)(Wh + (size_t)(m0 + row) * N + k0 + scol);
            short4v bp = { f2bf(bq.x), f2bf(bq.y), f2bf(bq.z), f2bf(bq.w) };
            *(short4v*)&Bs[row][scol] = bp;
        }
        __syncthreads();
#pragma unroll
        for (int ks = 0; ks < BK; ks += 32) {
            short8 af[4], bfr[4];
#pragma unroll
            for (int i = 0; i < 4; ++i)
                af[i] = *(const short8*)&As[wr + i * 16 + cm][ks + cq * 8];
#pragma unroll
            for (int j = 0; j < 4; ++j)
                bfr[j] = *(const short8*)&Bs[wm + j * 16 + cm][ks + cq * 8];
#pragma unroll
            for (int i = 0; i < 4; ++i)
#pragma unroll
                for (int j = 0; j < 4; ++j)
                    acc[i][j] = __builtin_amdgcn_mfma_f32_16x16x32_bf16(
                        af[i], bfr[j], acc[i][j], 0, 0, 0);
        }
        __syncthreads();
    }

    // Epilogue. C/D layout (verified m89/m91): col = lane&15, row = (lane>>4)*4 + reg.
    int b = r0 >> 12;                       // r0 / S; tiles never straddle batches
    const float* df = dec_feats + ((size_t)b << 10);

    float basej[4], wcj[4], vj[4];
#pragma unroll
    for (int j = 0; j < 4; ++j) {
        int m = m0 + wm + j * 16 + cm;
        basej[j] = bh[m] + df[m];
        wcj[j]   = wc[m];
        vj[j]    = v[m];
    }

#pragma unroll
    for (int i = 0; i < 4; ++i) {
        int rbase = r0 + wr + i * 16 + cq * 4;
        float cv[4];
#pragma unroll
        for (int reg = 0; reg < 4; ++reg) cv[reg] = cov[rbase + reg];
        float rs[4] = {0.f, 0.f, 0.f, 0.f};
#pragma unroll
        for (int j = 0; j < 4; ++j) {
#pragma unroll
            for (int reg = 0; reg < 4; ++reg) {
                float val = acc[i][j][reg] + basej[j] + cv[reg] * wcj[j];
                val = fminf(fmaxf(val, -30.f), 30.f);     // keep exp finite
                float texp = __expf(2.f * val);
                float th = (texp - 1.f) * __builtin_amdgcn_rcpf(texp + 1.f);
                rs[reg] += th * vj[j];
            }
        }
#pragma unroll
        for (int reg = 0; reg < 4; ++reg) {
            float p = rs[reg];
            p += __shfl_xor(p, 1);
            p += __shfl_xor(p, 2);
            p += __shfl_xor(p, 4);
            p += __shfl_xor(p, 8);
            if (cm == 0) atomicAdd(&e[rbase + reg], p);
        }
    }
}

// ---------------------------------------------------------------------------
// Kernel 3: masked softmax (renormalized masked softmax == plain masked
// softmax algebraically) + coverage update. One block per batch row.
// ---------------------------------------------------------------------------
__global__ __launch_bounds__(256)
void softmax_kernel(const float* __restrict__ e, const int* __restrict__ lens,
                    const float* __restrict__ cov,
                    float* __restrict__ attn, float* __restrict__ cov_out) {
    int b = blockIdx.x;
    int len = lens[b];
    const float* eb = e + (size_t)b * S;
    __shared__ float red[256];
    int t = threadIdx.x;

    float mx = -INFINITY;
    for (int s = t; s < S; s += 256)
        if (s < len) mx = fmaxf(mx, eb[s]);
    red[t] = mx; __syncthreads();
    for (int off = 128; off > 0; off >>= 1) {
        if (t < off) red[t] = fmaxf(red[t], red[t + off]);
        __syncthreads();
    }
    mx = red[0]; __syncthreads();

    float sum = 0.f;
    for (int s = t; s < S; s += 256)
        if (s < len) sum += __expf(eb[s] - mx);
    red[t] = sum; __syncthreads();
    for (int off = 128; off > 0; off >>= 1) {
        if (t < off) red[t] += red[t + off];
        __syncthreads();
    }
    float inv = 1.f / red[0];

    for (int s = t; s < S; s += 256) {
        float a = (s < len) ? __expf(eb[s] - mx) * inv : 0.f;
        attn[(size_t)b * S + s] = a;
        cov_out[(size_t)b * S + s] = cov[(size_t)b * S + s] + a;
    }
}

// ---------------------------------------------------------------------------
// Kernel 4: context[b][n] = sum_s attn[b][s] * enc[b][s][n]
// ---------------------------------------------------------------------------
#define SCH 32
__global__ __launch_bounds__(256)
void context_kernel(const float* __restrict__ attn, const float* __restrict__ enc,
                    float* __restrict__ ctx) {
    int b  = blockIdx.y;
    int s0 = blockIdx.x * (S / SCH);
    int n4 = threadIdx.x;
    const float4* ep = (const float4*)(enc + ((size_t)b * S + s0) * N);
    float4 acc = {0.f, 0.f, 0.f, 0.f};
    for (int s = 0; s < S / SCH; ++s) {
        float a = attn[(size_t)b * S + s0 + s];
        float4 ev = ep[(size_t)s * (N / 4) + n4];
        acc.x += a * ev.x; acc.y += a * ev.y;
        acc.z += a * ev.z; acc.w += a * ev.w;
    }
    float* cp = ctx + (size_t)b * N + n4 * 4;
    atomicAdd(cp + 0, acc.x);
    atomicAdd(cp + 1, acc.y);
    atomicAdd(cp + 2, acc.z);
    atomicAdd(cp + 3, acc.w);
}

// ---------------------------------------------------------------------------
extern "C" void kernel_launch(void* const* d_in, const int* in_sizes, int n_in,
                              void* d_out, int out_size, void* d_ws, size_t ws_size,
                              hipStream_t stream) {
    const float* dec  = (const float*)d_in[0];
    const float* enc  = (const float*)d_in[1];
    const int*   lens = (const int*)  d_in[2];
    const float* cov  = (const float*)d_in[3];
    const float* Wh   = (const float*)d_in[4];
    const float* bh   = (const float*)d_in[5];
    const float* Ws   = (const float*)d_in[6];
    const float* bs   = (const float*)d_in[7];
    const float* wc   = (const float*)d_in[8];
    const float* v    = (const float*)d_in[9];

    float* out     = (float*)d_out;
    float* ctx     = out;                    // B*N
    float* attn    = out + (size_t)B * N;    // B*S
    float* cov_out = attn + (size_t)B * S;   // B*S

    float* dec_feats = (float*)d_ws;                     // B*N floats
    float* e         = dec_feats + (size_t)B * N;        // B*S floats

    hipMemsetAsync(e, 0, (size_t)B * S * sizeof(float), stream);
    hipMemsetAsync(ctx, 0, (size_t)B * N * sizeof(float), stream);

    dec_feats_kernel<<<(B * N) / 256, 256, 0, stream>>>(dec, Ws, bs, dec_feats);
    score_mfma_kernel<<<(B * S / BR) * (N / BM), 256, 0, stream>>>(
        enc, Wh, bh, dec_feats, cov, wc, v, e);
    softmax_kernel<<<B, 256, 0, stream>>>(e, lens, cov, attn, cov_out);
    context_kernel<<<dim3(SCH, B), 256, 0, stream>>>(attn, enc, ctx);
}